// Round 6
// baseline (532.006 us; speedup 1.0000x reference)
//
#include <hip/hip_runtime.h>

#define A_DIM 6
#define HID_D 64
#define LATENT_D 64
#define GRU_IN_D 134
#define T_STEPS 128
#define N_ENV 10
#define BN_TOT 640

typedef float f2 __attribute__((ext_vector_type(2)));

// Pre-scaled transcendentals: log2e factors folded into weights/biases.
//   sig_pre(x)  == sigmoid(t) where x = -log2(e) * t
//   tanh_pre(y) == tanh(t)    where y =  2*log2(e) * t
#define KSIG (-1.4426950408889634f)
#define KTANH (2.8853900817779268f)
__device__ __forceinline__ float sig_pre(float x) {
    return __builtin_amdgcn_rcpf(1.0f + __builtin_amdgcn_exp2f(x));
}
__device__ __forceinline__ float tanh_pre(float y) {
    return fmaf(-2.0f, __builtin_amdgcn_rcpf(1.0f + __builtin_amdgcn_exp2f(y)), 1.0f);
}

template<int CTRL>
__device__ __forceinline__ float dppadd(float v) {
    int t = __builtin_amdgcn_update_dpp(0, __builtin_bit_cast(int, v), CTRL, 0xf, 0xf, true);
    return v + __builtin_bit_cast(float, t);
}
// sum over all 64 lanes -> wave-uniform scalar (VALU pipe only)
__device__ __forceinline__ float wave_reduce_add(float v) {
    v = dppadd<0x111>(v);   // row_shr:1
    v = dppadd<0x112>(v);   // row_shr:2
    v = dppadd<0x114>(v);   // row_shr:4
    v = dppadd<0x118>(v);   // row_shr:8
    v = dppadd<0x142>(v);   // row_bcast:15
    v = dppadd<0x143>(v);   // row_bcast:31 -> lane 63 has total
    return __builtin_bit_cast(float, __builtin_amdgcn_readlane(__builtin_bit_cast(int, v), 63));
}

// 4 waves cooperate on ONE rollout:
//   wave0: Whh_r sweep + gates a=0,1      wave1: Whh_z sweep + gates a=2,3
//   wave2: Whh_n sweep + gates a=4,5      wave3: mlp1 sweep + mlp2/argmax
// Per-wave weight residency: 64 VGPRs (one matrix row set) -> no spills.
__global__ __launch_bounds__(256)
void policy_kernel(const float* __restrict__ s_h,
                   const int*   __restrict__ a_h,
                   const float* __restrict__ b_z,
                   const float* __restrict__ conv1_w, const float* __restrict__ conv1_b,
                   const float* __restrict__ conv2_w, const float* __restrict__ conv2_b,
                   const float* __restrict__ fc_w,    const float* __restrict__ fc_b,
                   const float* __restrict__ emb,
                   const float* __restrict__ gru_wih, const float* __restrict__ gru_whh,
                   const float* __restrict__ gru_bih, const float* __restrict__ gru_bhh,
                   const float* __restrict__ mlp1_w,  const float* __restrict__ mlp1_b,
                   const float* __restrict__ mlp2_w,  const float* __restrict__ mlp2_b,
                   float* __restrict__ logits_out, float* __restrict__ mask_out)
{
    __shared__ __align__(16) float s0[512];       // frame0 [c][h][w]
    __shared__ __align__(16) float a1s[1152];     // conv1 out [32][36]
    __shared__ __align__(16) float a2s[512];      // conv2 out flat
    __shared__ __align__(16) float pfc[256];      // fc partials
    __shared__ __align__(16) float semb[64];
    __shared__ __align__(16) float gxc[192];      // step-invariant gx (+biases)
    __shared__ __align__(16) float hspec[6*64];   // speculative h candidates per action
    __shared__ __align__(16) float hrzn[3*64];    // per-step hr/hz/hn exchange
    __shared__ __align__(16) float llog[(T_STEPS-1)*A_DIM];  // logits buffer (762)
    __shared__ int act_lds;

    const int bn  = blockIdx.x;          // 0..639
    const int tid = threadIdx.x;         // 0..255
    const int j   = tid & 63;
    const int w   = tid >> 6;            // wave id 0..3

    // ---- masks output ----
    if (tid < 128)
        mask_out[bn * T_STEPS + tid] = (a_h[bn * T_STEPS + tid] != (A_DIM - 1)) ? 1.0f : 0.0f;

    // ---- load frame 0 ----
    {
        const float* src = s_h + (size_t)bn * T_STEPS * 512;
        s0[tid]       = src[tid];
        s0[tid + 256] = src[tid + 256];
    }
    __syncthreads();

    // ---- conv1: (8,8,8) -> (32,6,6), ReLU ----
    for (int i = tid; i < 1152; i += 256) {
        const int oc = i / 36, r = i % 36, oh = r / 6, ow = r % 6;
        float sum = conv1_b[oc];
        const float* wp = conv1_w + oc * 72;
        #pragma unroll
        for (int ic = 0; ic < 8; ++ic)
            #pragma unroll
            for (int kh = 0; kh < 3; ++kh)
                #pragma unroll
                for (int kw = 0; kw < 3; ++kw)
                    sum = fmaf(s0[ic * 64 + (oh + kh) * 8 + (ow + kw)],
                               wp[ic * 9 + kh * 3 + kw], sum);
        a1s[i] = fmaxf(sum, 0.0f);
    }
    __syncthreads();

    // ---- conv2: (32,6,6) -> (32,4,4), ReLU ----
    for (int i = tid; i < 512; i += 256) {
        const int oc = i / 16, r = i % 16, oh = r / 4, ow = r % 4;
        float sum = conv2_b[oc];
        const float* wp = conv2_w + oc * 288;
        for (int ic = 0; ic < 32; ++ic)
            #pragma unroll
            for (int kh = 0; kh < 3; ++kh)
                #pragma unroll
                for (int kw = 0; kw < 3; ++kw)
                    sum = fmaf(a1s[ic * 36 + (oh + kh) * 6 + (ow + kw)],
                               wp[ic * 9 + kh * 3 + kw], sum);
        a2s[i] = fmaxf(sum, 0.0f);
    }
    __syncthreads();

    // ---- fc: 512 -> 64, ReLU (k-split 4 ways across waves) ----
    {
        const float* wp = fc_w + j * 512 + w * 128;
        const float* ap = a2s + w * 128;
        float s0a = 0.f, s1a = 0.f, s2a = 0.f, s3a = 0.f;
        for (int k = 0; k < 128; k += 4) {
            s0a = fmaf(ap[k + 0], wp[k + 0], s0a);
            s1a = fmaf(ap[k + 1], wp[k + 1], s1a);
            s2a = fmaf(ap[k + 2], wp[k + 2], s2a);
            s3a = fmaf(ap[k + 3], wp[k + 3], s3a);
        }
        pfc[tid] = (s0a + s1a) + (s2a + s3a);
    }
    __syncthreads();
    if (tid < 64)
        semb[tid] = fmaxf(pfc[tid] + pfc[tid + 64] + pfc[tid + 128] + pfc[tid + 192]
                          + fc_b[tid], 0.0f);
    __syncthreads();

    // ---- step-invariant gx (one output per thread) ----
    if (tid < 192) {
        const float* bz = b_z + (size_t)(bn / N_ENV) * LATENT_D;
        const int g = tid;
        float sum = gru_bih[g] + ((g < 128) ? gru_bhh[g] : 0.0f);
        const float* wp = gru_wih + g * GRU_IN_D;
        for (int k = 0; k < 64; ++k) sum = fmaf(semb[k], wp[k], sum);
        for (int k = 0; k < 64; ++k) sum = fmaf(bz[k], wp[70 + k], sum);
        gxc[g] = sum;
    }
    __syncthreads();

    // ---- per-wave weight matrix (pre-scaled), 64 VGPRs ----
    f2 wm[32];
    {
        const float* src = (w == 0) ? gru_whh + (size_t)j * 64
                         : (w == 1) ? gru_whh + (size_t)(64 + j) * 64
                         : (w == 2) ? gru_whh + (size_t)(128 + j) * 64
                         :            mlp1_w  + (size_t)j * 64;
        const float ks = (w < 2) ? KSIG : KTANH;
        #pragma unroll
        for (int i = 0; i < 16; ++i) {
            const float4 v = ((const float4*)src)[i];
            wm[2*i]   = (f2){ks * v.x, ks * v.y};
            wm[2*i+1] = (f2){ks * v.z, ks * v.w};
        }
    }
    const float bhn_s = KTANH * gru_bhh[128 + j];   // scaled n-gate bias

    // per-wave step-invariant params
    float arx0 = 0.f, azx0 = 0.f, anx0 = 0.f;   // gate waves: action a0 = 2w
    float arx1 = 0.f, azx1 = 0.f, anx1 = 0.f;   // gate waves: action a1 = 2w+1
    float m2c[6], b2v[6];                        // wave3
    float b1s = 0.f;                             // wave3

    if (w < 3) {
        float wqr[6], wqz[6], wqn[6];
        #pragma unroll
        for (int q = 0; q < 6; ++q) {
            wqr[q] = gru_wih[j * GRU_IN_D + 64 + q];
            wqz[q] = gru_wih[(64 + j) * GRU_IN_D + 64 + q];
            wqn[q] = gru_wih[(128 + j) * GRU_IN_D + 64 + q];
        }
        const float gxr = gxc[j], gxz = gxc[64 + j], gxn = gxc[128 + j];
        #pragma unroll
        for (int s = 0; s < 2; ++s) {
            const int a = 2 * w + s;
            float sr = 0.f, sz = 0.f, sn = 0.f;
            #pragma unroll
            for (int q = 0; q < 6; ++q) {
                const float e = emb[a * 6 + q];
                sr = fmaf(e, wqr[q], sr);
                sz = fmaf(e, wqz[q], sz);
                sn = fmaf(e, wqn[q], sn);
            }
            if (s == 0) { arx0 = KSIG*(gxr+sr); azx0 = KSIG*(gxz+sz); anx0 = KTANH*(gxn+sn); }
            else        { arx1 = KSIG*(gxr+sr); azx1 = KSIG*(gxz+sz); anx1 = KTANH*(gxn+sn); }
        }
        // seed: h_1 candidates from h_0 = 0 (hr=hz=0, hn=bhn_s)
        {
            float r = sig_pre(arx0);
            float z = sig_pre(azx0);
            float n = tanh_pre(fmaf(r, bhn_s, anx0));
            hspec[(2*w) * 64 + j] = fmaf(z, 0.0f - n, n);
            r = sig_pre(arx1);
            z = sig_pre(azx1);
            n = tanh_pre(fmaf(r, bhn_s, anx1));
            hspec[(2*w+1) * 64 + j] = fmaf(z, 0.0f - n, n);
        }
    } else {
        #pragma unroll
        for (int a = 0; a < 6; ++a) { m2c[a] = mlp2_w[a * 64 + j]; b2v[a] = mlp2_b[a]; }
        b1s = KTANH * mlp1_b[j];
    }
    if (tid == 0) act_lds = A_DIM - 1;
    __syncthreads();

    // =========================== main rollout loop ===========================
    // NO VMEM ops inside: logits buffered in LDS, flushed after the loop.
    for (int t = 0; t < T_STEPS - 1; ++t) {
        // ---- phase 1: everyone sweeps its own matrix over chosen h ----
        const int act = act_lds;
        const float4* hb = (const float4*)(hspec + (act << 6));
        const float hprev = hspec[(act << 6) + j];   // lane's own h_{t+1}[j]

        f2 q0 = {0.f,0.f}, q1 = {0.f,0.f}, q2 = {0.f,0.f}, q3 = {0.f,0.f};
        #pragma unroll
        for (int i = 0; i < 8; ++i) {
            const float4 u = hb[i];
            const float4 v = hb[i + 8];
            q0 += (f2){u.x, u.y} * wm[2*i];
            q1 += (f2){u.z, u.w} * wm[2*i+1];
            q2 += (f2){v.x, v.y} * wm[2*i+16];
            q3 += (f2){v.z, v.w} * wm[2*i+17];
        }
        const f2 qs = (q0 + q1) + (q2 + q3);
        float sres = qs.x + qs.y;

        float hid = 0.0f;
        if (w == 2) sres += bhn_s;          // fold n-gate bias into hn
        if (w < 3)  hrzn[w * 64 + j] = sres;
        else        hid = tanh_pre(sres + b1s);
        __syncthreads();   // A: hr/hz/hn visible

        // ---- phase 2: gates (waves 0-2) || mlp2+argmax (wave3) ----
        if (w < 3) {
            const float hr = hrzn[j], hz = hrzn[64 + j], hn = hrzn[128 + j];
            float r = sig_pre(arx0 + hr);
            float z = sig_pre(azx0 + hz);
            float n = tanh_pre(fmaf(r, hn, anx0));
            hspec[(2*w) * 64 + j] = fmaf(z, hprev - n, n);
            r = sig_pre(arx1 + hr);
            z = sig_pre(azx1 + hz);
            n = tanh_pre(fmaf(r, hn, anx1));
            hspec[(2*w+1) * 64 + j] = fmaf(z, hprev - n, n);
        } else {
            const float l0 = wave_reduce_add(hid * m2c[0]) + b2v[0];
            const float l1 = wave_reduce_add(hid * m2c[1]) + b2v[1];
            const float l2 = wave_reduce_add(hid * m2c[2]) + b2v[2];
            const float l3 = wave_reduce_add(hid * m2c[3]) + b2v[3];
            const float l4 = wave_reduce_add(hid * m2c[4]) + b2v[4];
            const float l5 = wave_reduce_add(hid * m2c[5]) + b2v[5];

            if (j < A_DIM) {
                const float outv = (j == 0) ? l0 : (j == 1) ? l1 : (j == 2) ? l2
                                 : (j == 3) ? l3 : (j == 4) ? l4 : l5;
                llog[t * A_DIM + j] = outv;
            }
            // argmax, first-max-wins
            float best = l0; int bi = 0;
            if (l1 > best) { best = l1; bi = 1; }
            if (l2 > best) { best = l2; bi = 2; }
            if (l3 > best) { best = l3; bi = 3; }
            if (l4 > best) { best = l4; bi = 4; }
            if (l5 > best) { best = l5; bi = 5; }
            if (j == 0) act_lds = bi;
        }
        __syncthreads();   // B: hspec candidates + act visible
    }

    // ---- flush logits LDS -> global (coalesced) ----
    {
        float* lout = logits_out + (size_t)bn * (T_STEPS - 1) * A_DIM;
        for (int i = tid; i < (T_STEPS - 1) * A_DIM; i += 256) lout[i] = llog[i];
    }
}

extern "C" void kernel_launch(void* const* d_in, const int* in_sizes, int n_in,
                              void* d_out, int out_size, void* d_ws, size_t ws_size,
                              hipStream_t stream) {
    const float* s_h     = (const float*)d_in[0];
    const int*   a_h     = (const int*)  d_in[1];
    const float* b_z     = (const float*)d_in[2];
    const float* conv1_w = (const float*)d_in[3];
    const float* conv1_b = (const float*)d_in[4];
    const float* conv2_w = (const float*)d_in[5];
    const float* conv2_b = (const float*)d_in[6];
    const float* fc_w    = (const float*)d_in[7];
    const float* fc_b    = (const float*)d_in[8];
    const float* emb     = (const float*)d_in[9];
    const float* gru_wih = (const float*)d_in[10];
    const float* gru_whh = (const float*)d_in[11];
    const float* gru_bih = (const float*)d_in[12];
    const float* gru_bhh = (const float*)d_in[13];
    const float* mlp1_w  = (const float*)d_in[14];
    const float* mlp1_b  = (const float*)d_in[15];
    const float* mlp2_w  = (const float*)d_in[16];
    const float* mlp2_b  = (const float*)d_in[17];

    float* out = (float*)d_out;
    float* logits_out = out;                                          // (B,N,127,6)
    float* mask_out   = out + (size_t)BN_TOT * (T_STEPS - 1) * A_DIM; // (B,N,128,1)

    policy_kernel<<<BN_TOT, 256, 0, stream>>>(
        s_h, a_h, b_z, conv1_w, conv1_b, conv2_w, conv2_b, fc_w, fc_b, emb,
        gru_wih, gru_whh, gru_bih, gru_bhh, mlp1_w, mlp1_b, mlp2_w, mlp2_b,
        logits_out, mask_out);
}

// Round 8
// 453.478 us; speedup vs baseline: 1.1732x; 1.1732x over previous
//
#include <hip/hip_runtime.h>

#define A_DIM 6
#define HID_D 64
#define LATENT_D 64
#define GRU_IN_D 134
#define T_STEPS 128
#define N_ENV 10
#define BN_TOT 640

typedef float f2 __attribute__((ext_vector_type(2)));

__device__ __forceinline__ float fast_sigmoid(float x) {
    return __builtin_amdgcn_rcpf(1.0f + __builtin_amdgcn_exp2f(-1.4426950408889634f * x));
}
__device__ __forceinline__ float fast_tanh(float x) {
    return 1.0f - 2.0f * __builtin_amdgcn_rcpf(1.0f + __builtin_amdgcn_exp2f(2.8853900817779268f * x));
}

template<int CTRL>
__device__ __forceinline__ float dppadd(float v) {
    int t = __builtin_amdgcn_update_dpp(0, __builtin_bit_cast(int, v), CTRL, 0xf, 0xf, true);
    return v + __builtin_bit_cast(float, t);
}
// sum over all 64 lanes -> wave-uniform scalar (VALU pipe only)
__device__ __forceinline__ float wave_reduce_add(float v) {
    v = dppadd<0x111>(v);   // row_shr:1
    v = dppadd<0x112>(v);   // row_shr:2
    v = dppadd<0x114>(v);   // row_shr:4
    v = dppadd<0x118>(v);   // row_shr:8
    v = dppadd<0x142>(v);   // row_bcast:15
    v = dppadd<0x143>(v);   // row_bcast:31 -> lane 63 has total
    return __builtin_bit_cast(float, __builtin_amdgcn_readlane(__builtin_bit_cast(int, v), 63));
}

__global__ __launch_bounds__(128, 1)
void policy_kernel(const float* __restrict__ s_h,
                   const int*   __restrict__ a_h,
                   const float* __restrict__ b_z,
                   const float* __restrict__ conv1_w, const float* __restrict__ conv1_b,
                   const float* __restrict__ conv2_w, const float* __restrict__ conv2_b,
                   const float* __restrict__ fc_w,    const float* __restrict__ fc_b,
                   const float* __restrict__ emb,
                   const float* __restrict__ gru_wih, const float* __restrict__ gru_whh,
                   const float* __restrict__ gru_bih, const float* __restrict__ gru_bhh,
                   const float* __restrict__ mlp1_w,  const float* __restrict__ mlp1_b,
                   const float* __restrict__ mlp2_w,  const float* __restrict__ mlp2_b,
                   float* __restrict__ logits_out, float* __restrict__ mask_out)
{
    __shared__ __align__(16) float s0[512];      // frame0 [c][h][w]
    __shared__ __align__(16) float a1[1152];     // conv1 out [32][36]
    __shared__ __align__(16) float a2[512];      // conv2 out flat
    __shared__ __align__(16) float pfc[128];     // fc partials
    __shared__ __align__(16) float semb[64];
    __shared__ __align__(16) float gxc[192];     // step-invariant gx (+biases)
    __shared__ __align__(16) float atab[6*192];  // per-action gx contribution
    __shared__ __align__(16) float hspec[6*64];  // speculative h_{t+1} per action
    __shared__ __align__(16) float llog[(T_STEPS-1)*A_DIM];  // logits buffer (762)

    const int bn  = blockIdx.x;          // 0..639
    const int tid = threadIdx.x;         // 0..127 (preamble); rollout = wave 0 only
    const int j   = tid & 63;
    const int w   = tid >> 6;

    // ---- masks output ----
    mask_out[bn * T_STEPS + tid] = (a_h[bn * T_STEPS + tid] != (A_DIM - 1)) ? 1.0f : 0.0f;

    // ---- load frame 0 ----
    {
        const float* src = s_h + (size_t)bn * T_STEPS * 512;
        #pragma unroll
        for (int i = 0; i < 4; ++i) s0[tid + i * 128] = src[tid + i * 128];
    }
    __syncthreads();

    // ---- conv1: (8,8,8) -> (32,6,6), ReLU ----
    for (int i = tid; i < 1152; i += 128) {
        const int oc = i / 36, r = i % 36, oh = r / 6, ow = r % 6;
        float sum = conv1_b[oc];
        const float* wp = conv1_w + oc * 72;
        #pragma unroll
        for (int ic = 0; ic < 8; ++ic)
            #pragma unroll
            for (int kh = 0; kh < 3; ++kh)
                #pragma unroll
                for (int kw = 0; kw < 3; ++kw)
                    sum = fmaf(s0[ic * 64 + (oh + kh) * 8 + (ow + kw)],
                               wp[ic * 9 + kh * 3 + kw], sum);
        a1[i] = fmaxf(sum, 0.0f);
    }
    __syncthreads();

    // ---- conv2: (32,6,6) -> (32,4,4), ReLU ----
    for (int i = tid; i < 512; i += 128) {
        const int oc = i / 16, r = i % 16, oh = r / 4, ow = r % 4;
        float sum = conv2_b[oc];
        const float* wp = conv2_w + oc * 288;
        for (int ic = 0; ic < 32; ++ic)
            #pragma unroll
            for (int kh = 0; kh < 3; ++kh)
                #pragma unroll
                for (int kw = 0; kw < 3; ++kw)
                    sum = fmaf(a1[ic * 36 + (oh + kh) * 6 + (ow + kw)],
                               wp[ic * 9 + kh * 3 + kw], sum);
        a2[i] = fmaxf(sum, 0.0f);
    }
    __syncthreads();

    // ---- fc: 512 -> 64, ReLU (k-split across 2 waves) ----
    {
        const float* wp = fc_w + j * 512 + w * 256;
        const float* ap = a2 + w * 256;
        float s0a = 0.f, s1a = 0.f, s2a = 0.f, s3a = 0.f;
        for (int k = 0; k < 256; k += 4) {
            s0a = fmaf(ap[k + 0], wp[k + 0], s0a);
            s1a = fmaf(ap[k + 1], wp[k + 1], s1a);
            s2a = fmaf(ap[k + 2], wp[k + 2], s2a);
            s3a = fmaf(ap[k + 3], wp[k + 3], s3a);
        }
        pfc[tid] = (s0a + s1a) + (s2a + s3a);
    }
    __syncthreads();
    if (tid < 64) semb[tid] = fmaxf(pfc[tid] + pfc[tid + 64] + fc_b[tid], 0.0f);
    __syncthreads();

    // ---- step-invariant gx ----
    {
        const float* bz = b_z + (size_t)(bn / N_ENV) * LATENT_D;
        for (int g = tid; g < 192; g += 128) {
            float sum = gru_bih[g] + ((g < 128) ? gru_bhh[g] : 0.0f);
            const float* wp = gru_wih + g * GRU_IN_D;
            for (int k = 0; k < 64; ++k) sum = fmaf(semb[k], wp[k], sum);
            for (int k = 0; k < 64; ++k) sum = fmaf(bz[k], wp[70 + k], sum);
            gxc[g] = sum;
        }
    }
    // ---- action table ----
    for (int i = tid; i < 6 * 192; i += 128) {
        const int a = i / 192, g = i % 192;
        float sum = 0.0f;
        #pragma unroll
        for (int q = 0; q < 6; ++q)
            sum = fmaf(emb[a * 6 + q], gru_wih[g * GRU_IN_D + 64 + q], sum);
        atab[i] = sum;
    }
    __syncthreads();

    if (w == 1) return;   // rollout is single-wave; wave 1 exits

    // ---- per-lane fp32 weights ----
    f2 wr[32], wz[32], wn[32], w1[32];
    {
        const float* pr = gru_whh + (size_t)j * 64;
        const float* pz = gru_whh + (size_t)(64 + j) * 64;
        const float* pn = gru_whh + (size_t)(128 + j) * 64;
        const float* p1 = mlp1_w + (size_t)j * 64;
        #pragma unroll
        for (int i = 0; i < 16; ++i) {
            float4 v;
            v = ((const float4*)pr)[i]; wr[2*i] = (f2){v.x, v.y}; wr[2*i+1] = (f2){v.z, v.w};
            v = ((const float4*)pz)[i]; wz[2*i] = (f2){v.x, v.y}; wz[2*i+1] = (f2){v.z, v.w};
            v = ((const float4*)pn)[i]; wn[2*i] = (f2){v.x, v.y}; wn[2*i+1] = (f2){v.z, v.w};
            v = ((const float4*)p1)[i]; w1[2*i] = (f2){v.x, v.y}; w1[2*i+1] = (f2){v.z, v.w};
        }
    }
    const float bhn = gru_bhh[128 + j];
    const float b1j = mlp1_b[j];
    // step-invariant per-action gate inputs: arx[a] = gx_r + atab_r[a], etc.
    float arx[6], azx[6], anx[6], m2c[6], b2[6];
    {
        const float gxr = gxc[j], gxz = gxc[64 + j], gxn = gxc[128 + j];
        #pragma unroll
        for (int a = 0; a < 6; ++a) {
            arx[a] = gxr + atab[a * 192 + j];
            azx[a] = gxz + atab[a * 192 + 64 + j];
            anx[a] = gxn + atab[a * 192 + 128 + j];
            m2c[a] = mlp2_w[a * 64 + j];
            b2[a] = mlp2_b[a];
        }
    }

    // ---- seed: speculative h_1 candidates from h_0 = 0 ----
    float ha[6];
    #pragma unroll
    for (int a = 0; a < 6; ++a) {
        const float r = fast_sigmoid(arx[a]);
        const float z = fast_sigmoid(azx[a]);
        const float n = fast_tanh(fmaf(r, bhn, anx[a]));
        ha[a] = fmaf(z, 0.0f - n, n);            // (1-z)*n + z*0
    }
    __builtin_amdgcn_wave_barrier();
    #pragma unroll
    for (int a = 0; a < 6; ++a) hspec[a * 64 + j] = ha[a];
    __builtin_amdgcn_wave_barrier();

    int act = A_DIM - 1;

    for (int t = 0; t < T_STEPS - 1; ++t) {
        // critical path: act -> address -> batched load of h_{t+1} = hspec[act]
        const float4* hb = (const float4*)(hspec + (act << 6));
        // h_{t+1}[j] for this lane (for next speculative gates; off critical path)
        float hprev = ha[0];
        #pragma unroll
        for (int a = 1; a < 6; ++a) hprev = (act == a) ? ha[a] : hprev;

        // ---- FORCE-BATCHED h load: issue all 16 ds_read_b128, then a
        // scheduling fence. No instruction may cross sched_barrier(0), so
        // every load is issued before the first consuming FMA — the LDS
        // latency is exposed once, not up to 16 serial times.
        float4 h00 = hb[0],  h01 = hb[1],  h02 = hb[2],  h03 = hb[3];
        float4 h04 = hb[4],  h05 = hb[5],  h06 = hb[6],  h07 = hb[7];
        float4 h08 = hb[8],  h09 = hb[9],  h10 = hb[10], h11 = hb[11];
        float4 h12 = hb[12], h13 = hb[13], h14 = hb[14], h15 = hb[15];
        __builtin_amdgcn_sched_barrier(0);

        // fused sweep: mlp1 (2 chains, finishes first) + r/z/n dots
        f2 p1a = {0.f, 0.f}, p1b = {0.f, 0.f};
        f2 pr = {0.f, 0.f}, pz = {0.f, 0.f}, pn = {0.f, 0.f};
        #define SWEEP(i, hv) { \
            const f2 haa = (f2){hv.x, hv.y}; \
            const f2 hcc = (f2){hv.z, hv.w}; \
            p1a += haa * w1[2*(i)]; p1b += hcc * w1[2*(i)+1]; \
            pr += haa * wr[2*(i)]; pr += hcc * wr[2*(i)+1]; \
            pz += haa * wz[2*(i)]; pz += hcc * wz[2*(i)+1]; \
            pn += haa * wn[2*(i)]; pn += hcc * wn[2*(i)+1]; }
        SWEEP(0,  h00) SWEEP(1,  h01) SWEEP(2,  h02) SWEEP(3,  h03)
        SWEEP(4,  h04) SWEEP(5,  h05) SWEEP(6,  h06) SWEEP(7,  h07)
        SWEEP(8,  h08) SWEEP(9,  h09) SWEEP(10, h10) SWEEP(11, h11)
        SWEEP(12, h12) SWEEP(13, h13) SWEEP(14, h14) SWEEP(15, h15)
        #undef SWEEP
        const f2 p1 = p1a + p1b;
        const float hid = fast_tanh(p1.x + p1.y + b1j);
        const float hr = pr.x + pr.y;
        const float hz = pz.x + pz.y;
        const float hn = pn.x + pn.y + bhn;

        // mlp2 via DPP wave reduction (critical path: hid -> l -> argmax)
        const float l0 = wave_reduce_add(hid * m2c[0]) + b2[0];
        const float l1 = wave_reduce_add(hid * m2c[1]) + b2[1];
        const float l2 = wave_reduce_add(hid * m2c[2]) + b2[2];
        const float l3 = wave_reduce_add(hid * m2c[3]) + b2[3];
        const float l4 = wave_reduce_add(hid * m2c[4]) + b2[4];
        const float l5 = wave_reduce_add(hid * m2c[5]) + b2[5];

        // speculative gates for ALL 6 actions (independent of argmax; fills
        // the DPP latency window). Produces candidate h_{t+2} values.
        #pragma unroll
        for (int a = 0; a < 6; ++a) {
            const float r = fast_sigmoid(arx[a] + hr);
            const float z = fast_sigmoid(azx[a] + hz);
            const float n = fast_tanh(fmaf(r, hn, anx[a]));
            ha[a] = fmaf(z, hprev - n, n);
        }
        __builtin_amdgcn_wave_barrier();
        #pragma unroll
        for (int a = 0; a < 6; ++a) hspec[a * 64 + j] = ha[a];
        __builtin_amdgcn_wave_barrier();

        // argmax, first-max-wins
        float best = l0; int bi = 0;
        if (l1 > best) { best = l1; bi = 1; }
        if (l2 > best) { best = l2; bi = 2; }
        if (l3 > best) { best = l3; bi = 3; }
        if (l4 > best) { best = l4; bi = 4; }
        if (l5 > best) { best = l5; bi = 5; }
        act = bi;

        // logits -> LDS buffer (no VMEM in the loop; flushed after)
        if (j < A_DIM) {
            const float outv = (j == 0) ? l0 : (j == 1) ? l1 : (j == 2) ? l2
                             : (j == 3) ? l3 : (j == 4) ? l4 : l5;
            llog[t * A_DIM + j] = outv;
        }
    }

    // ---- flush logits LDS -> global (coalesced, once) ----
    {
        float* lout = logits_out + (size_t)bn * (T_STEPS - 1) * A_DIM;
        for (int i = j; i < (T_STEPS - 1) * A_DIM; i += 64) lout[i] = llog[i];
    }
}

extern "C" void kernel_launch(void* const* d_in, const int* in_sizes, int n_in,
                              void* d_out, int out_size, void* d_ws, size_t ws_size,
                              hipStream_t stream) {
    const float* s_h     = (const float*)d_in[0];
    const int*   a_h     = (const int*)  d_in[1];
    const float* b_z     = (const float*)d_in[2];
    const float* conv1_w = (const float*)d_in[3];
    const float* conv1_b = (const float*)d_in[4];
    const float* conv2_w = (const float*)d_in[5];
    const float* conv2_b = (const float*)d_in[6];
    const float* fc_w    = (const float*)d_in[7];
    const float* fc_b    = (const float*)d_in[8];
    const float* emb     = (const float*)d_in[9];
    const float* gru_wih = (const float*)d_in[10];
    const float* gru_whh = (const float*)d_in[11];
    const float* gru_bih = (const float*)d_in[12];
    const float* gru_bhh = (const float*)d_in[13];
    const float* mlp1_w  = (const float*)d_in[14];
    const float* mlp1_b  = (const float*)d_in[15];
    const float* mlp2_w  = (const float*)d_in[16];
    const float* mlp2_b  = (const float*)d_in[17];

    float* out = (float*)d_out;
    float* logits_out = out;                                          // (B,N,127,6)
    float* mask_out   = out + (size_t)BN_TOT * (T_STEPS - 1) * A_DIM; // (B,N,128,1)

    policy_kernel<<<BN_TOT, 128, 0, stream>>>(
        s_h, a_h, b_z, conv1_w, conv1_b, conv2_w, conv2_b, fc_w, fc_b, emb,
        gru_wih, gru_whh, gru_bih, gru_bhh, mlp1_w, mlp1_b, mlp2_w, mlp2_b,
        logits_out, mask_out);
}

// Round 9
// 422.298 us; speedup vs baseline: 1.2598x; 1.0738x over previous
//
#include <hip/hip_runtime.h>

#define A_DIM 6
#define HID_D 64
#define LATENT_D 64
#define GRU_IN_D 134
#define T_STEPS 128
#define N_ENV 10
#define BN_TOT 640

typedef float f2 __attribute__((ext_vector_type(2)));

__device__ __forceinline__ float fast_sigmoid(float x) {
    return __builtin_amdgcn_rcpf(1.0f + __builtin_amdgcn_exp2f(-1.4426950408889634f * x));
}
__device__ __forceinline__ float fast_tanh(float x) {
    return 1.0f - 2.0f * __builtin_amdgcn_rcpf(1.0f + __builtin_amdgcn_exp2f(2.8853900817779268f * x));
}

template<int CTRL>
__device__ __forceinline__ float dppadd(float v) {
    int t = __builtin_amdgcn_update_dpp(0, __builtin_bit_cast(int, v), CTRL, 0xf, 0xf, true);
    return v + __builtin_bit_cast(float, t);
}
// sum over all 64 lanes -> wave-uniform scalar (VALU pipe only)
__device__ __forceinline__ float wave_reduce_add(float v) {
    v = dppadd<0x111>(v);   // row_shr:1
    v = dppadd<0x112>(v);   // row_shr:2
    v = dppadd<0x114>(v);   // row_shr:4
    v = dppadd<0x118>(v);   // row_shr:8
    v = dppadd<0x142>(v);   // row_bcast:15
    v = dppadd<0x143>(v);   // row_bcast:31 -> lane 63 has total
    return __builtin_bit_cast(float, __builtin_amdgcn_readlane(__builtin_bit_cast(int, v), 63));
}

__global__ __launch_bounds__(128, 1)
void policy_kernel(const float* __restrict__ s_h,
                   const int*   __restrict__ a_h,
                   const float* __restrict__ b_z,
                   const float* __restrict__ conv1_w, const float* __restrict__ conv1_b,
                   const float* __restrict__ conv2_w, const float* __restrict__ conv2_b,
                   const float* __restrict__ fc_w,    const float* __restrict__ fc_b,
                   const float* __restrict__ emb,
                   const float* __restrict__ gru_wih, const float* __restrict__ gru_whh,
                   const float* __restrict__ gru_bih, const float* __restrict__ gru_bhh,
                   const float* __restrict__ mlp1_w,  const float* __restrict__ mlp1_b,
                   const float* __restrict__ mlp2_w,  const float* __restrict__ mlp2_b,
                   float* __restrict__ logits_out, float* __restrict__ mask_out)
{
    __shared__ __align__(16) float s0[512];      // frame0 [c][h][w]
    __shared__ __align__(16) float a1[1152];     // conv1 out [32][36]
    __shared__ __align__(16) float a2[512];      // conv2 out flat
    __shared__ __align__(16) float pfc[128];     // fc partials
    __shared__ __align__(16) float semb[64];
    __shared__ __align__(16) float gxc[192];     // step-invariant gx (+biases)
    __shared__ __align__(16) float atab[6*192];  // per-action gx contribution
    __shared__ __align__(16) float h_lds[64];    // current h broadcast buffer
    __shared__ __align__(16) float llog[(T_STEPS-1)*A_DIM];  // logits buffer (762)

    const int bn  = blockIdx.x;          // 0..639
    const int tid = threadIdx.x;         // 0..127 (preamble); rollout = wave 0 only
    const int j   = tid & 63;
    const int w   = tid >> 6;

    // ---- masks output ----
    mask_out[bn * T_STEPS + tid] = (a_h[bn * T_STEPS + tid] != (A_DIM - 1)) ? 1.0f : 0.0f;

    // ---- load frame 0 ----
    {
        const float* src = s_h + (size_t)bn * T_STEPS * 512;
        #pragma unroll
        for (int i = 0; i < 4; ++i) s0[tid + i * 128] = src[tid + i * 128];
    }
    __syncthreads();

    // ---- conv1: (8,8,8) -> (32,6,6), ReLU ----
    for (int i = tid; i < 1152; i += 128) {
        const int oc = i / 36, r = i % 36, oh = r / 6, ow = r % 6;
        float sum = conv1_b[oc];
        const float* wp = conv1_w + oc * 72;
        #pragma unroll
        for (int ic = 0; ic < 8; ++ic)
            #pragma unroll
            for (int kh = 0; kh < 3; ++kh)
                #pragma unroll
                for (int kw = 0; kw < 3; ++kw)
                    sum = fmaf(s0[ic * 64 + (oh + kh) * 8 + (ow + kw)],
                               wp[ic * 9 + kh * 3 + kw], sum);
        a1[i] = fmaxf(sum, 0.0f);
    }
    __syncthreads();

    // ---- conv2: (32,6,6) -> (32,4,4), ReLU ----
    for (int i = tid; i < 512; i += 128) {
        const int oc = i / 16, r = i % 16, oh = r / 4, ow = r % 4;
        float sum = conv2_b[oc];
        const float* wp = conv2_w + oc * 288;
        for (int ic = 0; ic < 32; ++ic)
            #pragma unroll
            for (int kh = 0; kh < 3; ++kh)
                #pragma unroll
                for (int kw = 0; kw < 3; ++kw)
                    sum = fmaf(a1[ic * 36 + (oh + kh) * 6 + (ow + kw)],
                               wp[ic * 9 + kh * 3 + kw], sum);
        a2[i] = fmaxf(sum, 0.0f);
    }
    __syncthreads();

    // ---- fc: 512 -> 64, ReLU (k-split across 2 waves) ----
    {
        const float* wp = fc_w + j * 512 + w * 256;
        const float* ap = a2 + w * 256;
        float s0a = 0.f, s1a = 0.f, s2a = 0.f, s3a = 0.f;
        for (int k = 0; k < 256; k += 4) {
            s0a = fmaf(ap[k + 0], wp[k + 0], s0a);
            s1a = fmaf(ap[k + 1], wp[k + 1], s1a);
            s2a = fmaf(ap[k + 2], wp[k + 2], s2a);
            s3a = fmaf(ap[k + 3], wp[k + 3], s3a);
        }
        pfc[tid] = (s0a + s1a) + (s2a + s3a);
    }
    __syncthreads();
    if (tid < 64) semb[tid] = fmaxf(pfc[tid] + pfc[tid + 64] + fc_b[tid], 0.0f);
    __syncthreads();

    // ---- step-invariant gx ----
    {
        const float* bz = b_z + (size_t)(bn / N_ENV) * LATENT_D;
        for (int g = tid; g < 192; g += 128) {
            float sum = gru_bih[g] + ((g < 128) ? gru_bhh[g] : 0.0f);
            const float* wp = gru_wih + g * GRU_IN_D;
            for (int k = 0; k < 64; ++k) sum = fmaf(semb[k], wp[k], sum);
            for (int k = 0; k < 64; ++k) sum = fmaf(bz[k], wp[70 + k], sum);
            gxc[g] = sum;
        }
    }
    // ---- action table ----
    for (int i = tid; i < 6 * 192; i += 128) {
        const int a = i / 192, g = i % 192;
        float sum = 0.0f;
        #pragma unroll
        for (int q = 0; q < 6; ++q)
            sum = fmaf(emb[a * 6 + q], gru_wih[g * GRU_IN_D + 64 + q], sum);
        atab[i] = sum;
    }
    __syncthreads();

    if (w == 1) return;   // rollout is single-wave; wave 1 exits

    // ---- per-lane fp32 weights ----
    f2 wr[32], wz[32], wn[32], w1[32];
    {
        const float* pr = gru_whh + (size_t)j * 64;
        const float* pz = gru_whh + (size_t)(64 + j) * 64;
        const float* pn = gru_whh + (size_t)(128 + j) * 64;
        const float* p1 = mlp1_w + (size_t)j * 64;
        #pragma unroll
        for (int i = 0; i < 16; ++i) {
            float4 v;
            v = ((const float4*)pr)[i]; wr[2*i] = (f2){v.x, v.y}; wr[2*i+1] = (f2){v.z, v.w};
            v = ((const float4*)pz)[i]; wz[2*i] = (f2){v.x, v.y}; wz[2*i+1] = (f2){v.z, v.w};
            v = ((const float4*)pn)[i]; wn[2*i] = (f2){v.x, v.y}; wn[2*i+1] = (f2){v.z, v.w};
            v = ((const float4*)p1)[i]; w1[2*i] = (f2){v.x, v.y}; w1[2*i+1] = (f2){v.z, v.w};
        }
    }
    const float bhn = gru_bhh[128 + j];
    const float b1j = mlp1_b[j];
    // step-invariant per-action gate inputs: arx[a] = gx_r + atab_r[a], etc.
    float arx[6], azx[6], anx[6], m2c[6], b2[6];
    {
        const float gxr = gxc[j], gxz = gxc[64 + j], gxn = gxc[128 + j];
        #pragma unroll
        for (int a = 0; a < 6; ++a) {
            arx[a] = gxr + atab[a * 192 + j];
            azx[a] = gxz + atab[a * 192 + 64 + j];
            anx[a] = gxn + atab[a * 192 + 128 + j];
            m2c[a] = mlp2_w[a * 64 + j];
            b2[a] = mlp2_b[a];
        }
    }

    // ---- seed: h_1 = GRU(h_0 = 0, act = 5): hr = hz = 0, hn = bhn ----
    float hprev;
    {
        const float r = fast_sigmoid(arx[5]);
        const float z = fast_sigmoid(azx[5]);
        const float n = fast_tanh(fmaf(r, bhn, anx[5]));
        hprev = fmaf(z, 0.0f - n, n);            // (1-z)*n + z*0
    }
    __builtin_amdgcn_wave_barrier();
    h_lds[j] = hprev;
    __builtin_amdgcn_wave_barrier();

    for (int t = 0; t < T_STEPS - 1; ++t) {
        // ---- batched broadcast load of h (uniform addresses, one wait) ----
        const float4* hb = (const float4*)h_lds;
        float4 h00 = hb[0],  h01 = hb[1],  h02 = hb[2],  h03 = hb[3];
        float4 h04 = hb[4],  h05 = hb[5],  h06 = hb[6],  h07 = hb[7];
        float4 h08 = hb[8],  h09 = hb[9],  h10 = hb[10], h11 = hb[11];
        float4 h12 = hb[12], h13 = hb[13], h14 = hb[14], h15 = hb[15];
        __builtin_amdgcn_sched_barrier(0);

        // ---- fused sweep, split chains: p1 4-way (8-deep), r/z/n 2-way (16-deep)
        f2 p1a = {0.f,0.f}, p1b = {0.f,0.f}, p1c = {0.f,0.f}, p1d = {0.f,0.f};
        f2 pra = {0.f,0.f}, prb = {0.f,0.f};
        f2 pza = {0.f,0.f}, pzb = {0.f,0.f};
        f2 pna = {0.f,0.f}, pnb = {0.f,0.f};
        #define SWEEPA(i, hv) { \
            const f2 haa = (f2){hv.x, hv.y}; \
            const f2 hcc = (f2){hv.z, hv.w}; \
            p1a += haa * w1[2*(i)]; p1b += hcc * w1[2*(i)+1]; \
            pra += haa * wr[2*(i)]; prb += hcc * wr[2*(i)+1]; \
            pza += haa * wz[2*(i)]; pzb += hcc * wz[2*(i)+1]; \
            pna += haa * wn[2*(i)]; pnb += hcc * wn[2*(i)+1]; }
        #define SWEEPB(i, hv) { \
            const f2 haa = (f2){hv.x, hv.y}; \
            const f2 hcc = (f2){hv.z, hv.w}; \
            p1c += haa * w1[2*(i)]; p1d += hcc * w1[2*(i)+1]; \
            pra += haa * wr[2*(i)]; prb += hcc * wr[2*(i)+1]; \
            pza += haa * wz[2*(i)]; pzb += hcc * wz[2*(i)+1]; \
            pna += haa * wn[2*(i)]; pnb += hcc * wn[2*(i)+1]; }
        SWEEPA(0,  h00) SWEEPA(1,  h01) SWEEPA(2,  h02) SWEEPA(3,  h03)
        SWEEPA(4,  h04) SWEEPA(5,  h05) SWEEPA(6,  h06) SWEEPA(7,  h07)
        SWEEPB(8,  h08) SWEEPB(9,  h09) SWEEPB(10, h10) SWEEPB(11, h11)
        SWEEPB(12, h12) SWEEPB(13, h13) SWEEPB(14, h14) SWEEPB(15, h15)
        #undef SWEEPA
        #undef SWEEPB
        const f2 p1 = (p1a + p1b) + (p1c + p1d);
        const float hid = fast_tanh(p1.x + p1.y + b1j);
        const f2 prf = pra + prb;
        const f2 pzf = pza + pzb;
        const f2 pnf = pna + pnb;
        const float hr = prf.x + prf.y;
        const float hz = pzf.x + pzf.y;
        const float hn = pnf.x + pnf.y + bhn;

        // ---- mlp2 via DPP wave reduction (critical path: hid -> l -> argmax)
        const float l0 = wave_reduce_add(hid * m2c[0]) + b2[0];
        const float l1 = wave_reduce_add(hid * m2c[1]) + b2[1];
        const float l2 = wave_reduce_add(hid * m2c[2]) + b2[2];
        const float l3 = wave_reduce_add(hid * m2c[3]) + b2[3];
        const float l4 = wave_reduce_add(hid * m2c[4]) + b2[4];
        const float l5 = wave_reduce_add(hid * m2c[5]) + b2[5];

        // logits -> LDS buffer (off critical path; no VMEM in the loop)
        if (j < A_DIM) {
            const float outv = (j == 0) ? l0 : (j == 1) ? l1 : (j == 2) ? l2
                             : (j == 3) ? l3 : (j == 4) ? l4 : l5;
            llog[t * A_DIM + j] = outv;
        }

        // ---- argmax tree (first-max-wins) carrying the selected gate inputs
        // level 1
        const bool c01 = l1 > l0;
        const float m01 = c01 ? l1 : l0;
        float sr = c01 ? arx[1] : arx[0];
        float sz = c01 ? azx[1] : azx[0];
        float sn = c01 ? anx[1] : anx[0];
        const bool c23 = l3 > l2;
        const float m23 = c23 ? l3 : l2;
        const float sr23 = c23 ? arx[3] : arx[2];
        const float sz23 = c23 ? azx[3] : azx[2];
        const float sn23 = c23 ? anx[3] : anx[2];
        const bool c45 = l5 > l4;
        const float m45 = c45 ? l5 : l4;
        const float sr45 = c45 ? arx[5] : arx[4];
        const float sz45 = c45 ? azx[5] : azx[4];
        const float sn45 = c45 ? anx[5] : anx[4];
        // level 2
        const bool cA = m23 > m01;
        const float mA = cA ? m23 : m01;
        sr = cA ? sr23 : sr;
        sz = cA ? sz23 : sz;
        sn = cA ? sn23 : sn;
        // level 3
        const bool cB = m45 > mA;
        sr = cB ? sr45 : sr;
        sz = cB ? sz45 : sz;
        sn = cB ? sn45 : sn;

        // ---- single-action gates for the chosen action ----
        const float r = fast_sigmoid(sr + hr);
        const float z = fast_sigmoid(sz + hz);
        const float n = fast_tanh(fmaf(r, hn, sn));
        const float hnew = fmaf(z, hprev - n, n);

        __builtin_amdgcn_wave_barrier();
        h_lds[j] = hnew;
        hprev = hnew;
        __builtin_amdgcn_wave_barrier();
    }

    // ---- flush logits LDS -> global (coalesced, once) ----
    {
        float* lout = logits_out + (size_t)bn * (T_STEPS - 1) * A_DIM;
        for (int i = j; i < (T_STEPS - 1) * A_DIM; i += 64) lout[i] = llog[i];
    }
}

extern "C" void kernel_launch(void* const* d_in, const int* in_sizes, int n_in,
                              void* d_out, int out_size, void* d_ws, size_t ws_size,
                              hipStream_t stream) {
    const float* s_h     = (const float*)d_in[0];
    const int*   a_h     = (const int*)  d_in[1];
    const float* b_z     = (const float*)d_in[2];
    const float* conv1_w = (const float*)d_in[3];
    const float* conv1_b = (const float*)d_in[4];
    const float* conv2_w = (const float*)d_in[5];
    const float* conv2_b = (const float*)d_in[6];
    const float* fc_w    = (const float*)d_in[7];
    const float* fc_b    = (const float*)d_in[8];
    const float* emb     = (const float*)d_in[9];
    const float* gru_wih = (const float*)d_in[10];
    const float* gru_whh = (const float*)d_in[11];
    const float* gru_bih = (const float*)d_in[12];
    const float* gru_bhh = (const float*)d_in[13];
    const float* mlp1_w  = (const float*)d_in[14];
    const float* mlp1_b  = (const float*)d_in[15];
    const float* mlp2_w  = (const float*)d_in[16];
    const float* mlp2_b  = (const float*)d_in[17];

    float* out = (float*)d_out;
    float* logits_out = out;                                          // (B,N,127,6)
    float* mask_out   = out + (size_t)BN_TOT * (T_STEPS - 1) * A_DIM; // (B,N,128,1)

    policy_kernel<<<BN_TOT, 128, 0, stream>>>(
        s_h, a_h, b_z, conv1_w, conv1_b, conv2_w, conv2_b, fc_w, fc_b, emb,
        gru_wih, gru_whh, gru_bih, gru_bhh, mlp1_w, mlp1_b, mlp2_w, mlp2_b,
        logits_out, mask_out);
}